// Round 12
// baseline (339.600 us; speedup 1.0000x reference)
//
#include <hip/hip_runtime.h>

#define N_NODES 50000
#define N_EDGES 1600000
#define R_REL 4
#define F_IN 32
#define H1 32
#define H2 64
#define NC 3
#define G_BATCH 64
#define BKT 196                        // buckets = ceil(N/256)
#define BCAP 8960                      // fixed slice capacity (mean 8192 + 8.5 sigma)
#define CHUNK 6400                     // edges per binning block
#define NBIN (N_EDGES / CHUNK)         // 250 exactly
#define ELIST_CAP (N_EDGES + N_NODES * R_REL * 8)

// ---------------- 0. padded copy of x + zero rows + cursor init ----------------
__global__ __launch_bounds__(256) void copyx_kernel(const float* __restrict__ x,
                                                    float* __restrict__ xp,
                                                    float* __restrict__ h1zero,
                                                    int* __restrict__ bucketCursor) {
    int i = blockIdx.x * 256 + threadIdx.x;
    if (i < (N_NODES + 1) * F_IN)
        xp[i] = (i < N_NODES * F_IN) ? x[i] : 0.0f;
    if (i < H1) h1zero[i] = 0.0f;      // h1 row N (sentinel row for layer 2)
    if (i < BKT) bucketCursor[i] = i * BCAP;   // fixed-capacity slice bases
}

// ---------------- 1. bin edges: LDS counting sort -> coalesced slice writes ---
// record = src | type<<16 | dstLocal<<18. Fixed BCAP slices: no bcount/bscan.
__global__ __launch_bounds__(256) void bin_kernel(const int* __restrict__ srcp,
                                                  const int* __restrict__ dstp,
                                                  const int* __restrict__ etype,
                                                  int* __restrict__ bucketCursor,
                                                  int* __restrict__ binned) {
    __shared__ int hist[256];
    __shared__ int lofs[256];          // inclusive scan of hist
    __shared__ int gbase[BKT];
    __shared__ int lcur[BKT];
    __shared__ int recs[CHUNK];        // 25.6 KB
    int t = threadIdx.x;
    hist[t] = 0;
    if (t < BKT) lcur[t] = 0;
    __syncthreads();
    int e0 = blockIdx.x * CHUNK;
    for (int e = e0 + t; e < e0 + CHUNK; e += 256)
        atomicAdd(&hist[dstp[e] >> 8], 1);
    __syncthreads();
    int v = hist[t];
    lofs[t] = v;
    __syncthreads();
    for (int w = 1; w < 256; w <<= 1) {
        int tv = (t >= w) ? lofs[t - w] : 0;
        __syncthreads();
        lofs[t] += tv;
        __syncthreads();
    }
    if (t < BKT) gbase[t] = v ? atomicAdd(&bucketCursor[t], v) : 0;
    __syncthreads();
    for (int e = e0 + t; e < e0 + CHUNK; e += 256) {
        int d = dstp[e];
        int b = d >> 8;
        int r = atomicAdd(&lcur[b], 1);
        recs[lofs[b] - hist[b] + r] =
            srcp[e] | (etype[e] << 16) | ((d & 0xFF) << 18);
    }
    __syncthreads();
    for (int b = 0; b < BKT; ++b) {    // coalesced per-bucket burst copy
        int cnt = hist[b];
        int lo = lofs[b] - cnt;
        int gb = gbase[b];
        for (int i = t; i < cnt; i += 256) binned[gb + i] = recs[lo + i];
    }
}

// ---------------- 2. per-(node,rel) counts + inv + padded-degree sums --------
__global__ __launch_bounds__(256) void bcnt2_kernel(const int* __restrict__ binned,
                                                    const int* __restrict__ bucketCursor,
                                                    float* __restrict__ inv,
                                                    int* __restrict__ rcnt4,
                                                    int* __restrict__ partial) {
    __shared__ int cnt4[256 * R_REL];
    __shared__ int s[256];
    for (int i = threadIdx.x; i < 256 * R_REL; i += 256) cnt4[i] = 0;
    __syncthreads();
    int b = blockIdx.x;
    int i0 = b * BCAP, i1 = bucketCursor[b];
    for (int i = i0 + threadIdx.x; i < i1; i += 256) {
        int p = binned[i];
        atomicAdd(&cnt4[((p >> 18) & 0xFF) * R_REL + ((p >> 16) & 3)], 1);
    }
    __syncthreads();
    int n = b * 256 + threadIdx.x;
    int d = 0;
    if (n < N_NODES) {
        int4 w;
        int c0 = cnt4[threadIdx.x * 4 + 0];
        int c1 = cnt4[threadIdx.x * 4 + 1];
        int c2 = cnt4[threadIdx.x * 4 + 2];
        int c3 = cnt4[threadIdx.x * 4 + 3];
        inv[0 * N_NODES + n] = 1.0f / (float)(c0 > 1 ? c0 : 1);
        inv[1 * N_NODES + n] = 1.0f / (float)(c1 > 1 ? c1 : 1);
        inv[2 * N_NODES + n] = 1.0f / (float)(c2 > 1 ? c2 : 1);
        inv[3 * N_NODES + n] = 1.0f / (float)(c3 > 1 ? c3 : 1);
        w.x = c0; w.y = c1; w.z = c2; w.w = c3;
        *(int4*)&rcnt4[n * 4] = w;
        d = ((c0 + 7) & ~7) + ((c1 + 7) & ~7) + ((c2 + 7) & ~7) + ((c3 + 7) & ~7);
    }
    s[threadIdx.x] = d;
    __syncthreads();
    for (int w = 128; w > 0; w >>= 1) {
        if (threadIdx.x < w) s[threadIdx.x] += s[threadIdx.x + w];
        __syncthreads();
    }
    if (threadIdx.x == 0) partial[b] = s[0];
}

// ---------------- 3. scan of block sums (exclusive), one block ----------------
__global__ __launch_bounds__(256) void scanB_kernel(int* __restrict__ partial) {
    __shared__ int s[256];
    int v = (threadIdx.x < BKT) ? partial[threadIdx.x] : 0;
    s[threadIdx.x] = v;
    __syncthreads();
    for (int w = 1; w < 256; w <<= 1) {
        int t = (threadIdx.x >= w) ? s[threadIdx.x - w] : 0;
        __syncthreads();
        s[threadIdx.x] += t;
        __syncthreads();
    }
    if (threadIdx.x < BKT) partial[threadIdx.x] = s[threadIdx.x] - v;  // exclusive
}

// ---------------- 4. per-(node,rel) padded sub-offsets ----------------
__global__ __launch_bounds__(256) void scanC_kernel(const int* __restrict__ rcnt4,
                                                    const int* __restrict__ partial,
                                                    int* __restrict__ poff4) {
    __shared__ int s[256];
    int n = blockIdx.x * 256 + threadIdx.x;
    int p0 = 0, p1 = 0, p2 = 0, p3 = 0, d = 0;
    if (n < N_NODES) {
        int4 rc = *(const int4*)&rcnt4[n * 4];
        p0 = (rc.x + 7) & ~7;
        p1 = (rc.y + 7) & ~7;
        p2 = (rc.z + 7) & ~7;
        p3 = (rc.w + 7) & ~7;
        d = p0 + p1 + p2 + p3;
    }
    s[threadIdx.x] = d;
    __syncthreads();
    for (int w = 1; w < 256; w <<= 1) {
        int t = (threadIdx.x >= w) ? s[threadIdx.x - w] : 0;
        __syncthreads();
        s[threadIdx.x] += t;
        __syncthreads();
    }
    if (n < N_NODES) {
        int base = partial[blockIdx.x] + s[threadIdx.x] - d;
        int4 w;
        w.x = base;
        w.y = base + p0;
        w.z = base + p0 + p1;
        w.w = base + p0 + p1 + p2;
        *(int4*)&poff4[n * 4] = w;
    }
}

// ---------------- 5. final CSR scatter, rel-sorted + sentinel padding --------
__global__ __launch_bounds__(256) void bscatter_kernel(const int* __restrict__ binned,
                                                       const int* __restrict__ bucketCursor,
                                                       const int* __restrict__ poff4,
                                                       const int* __restrict__ rcnt4,
                                                       int* __restrict__ elist) {
    __shared__ int cur[256 * 4];
    int b = blockIdx.x, t = threadIdx.x;
    int n = b * 256 + t;
    int4 po = make_int4(0, 0, 0, 0);
    if (n < N_NODES) po = *(const int4*)&poff4[n * 4];
    cur[t * 4 + 0] = po.x;
    cur[t * 4 + 1] = po.y;
    cur[t * 4 + 2] = po.z;
    cur[t * 4 + 3] = po.w;
    __syncthreads();
    int i0 = b * BCAP, i1 = bucketCursor[b];
    for (int i = i0 + t; i < i1; i += 256) {
        int p = binned[i];
        int pos = atomicAdd(&cur[((p >> 18) & 0xFF) * 4 + ((p >> 16) & 3)], 1);
        elist[pos] = p & 0xFFFF;       // src only (rel implied by segment)
    }
    __syncthreads();
    if (n < N_NODES) {
        int4 rc = *(const int4*)&rcnt4[n * 4];
        int rcv[4] = {rc.x, rc.y, rc.z, rc.w};
        int pov[4] = {po.x, po.y, po.z, po.w};
#pragma unroll
        for (int r = 0; r < R_REL; ++r) {
            int e = cur[t * 4 + r];
            int pe = pov[r] + ((rcv[r] + 7) & ~7);
            for (; e < pe; ++e) elist[e] = N_NODES;   // zero-row sentinel
        }
    }
}

// ---------------- wave helpers ----------------
__device__ __forceinline__ void red4(float4& a) {
#pragma unroll
    for (int st = 8; st < 64; st <<= 1) {
        a.x += __shfl_xor(a.x, st);
        a.y += __shfl_xor(a.y, st);
        a.z += __shfl_xor(a.z, st);
        a.w += __shfl_xor(a.w, st);
    }
}
__device__ __forceinline__ void acc4(float4& a, const float4 v) {
    a.x += v.x; a.y += v.y; a.z += v.z; a.w += v.w;
}

// ---------------- 6. layer 1: one wave per node, float4 gathers --------------
// At the per-CU outstanding-miss floor (R11): structure frozen.
__global__ __launch_bounds__(256, 4) void layer1_kernel(
    const float* __restrict__ xp, const int* __restrict__ poff4,
    const int* __restrict__ rcnt4, const int* __restrict__ elist,
    const float* __restrict__ inv, const float* __restrict__ W_rel,
    const float* __restrict__ W_root, const float* __restrict__ bb,
    float* __restrict__ h1) {
    __shared__ float sxr[4][F_IN];
    __shared__ float sagg[4][R_REL][F_IN];
    int wid = threadIdx.x >> 6, lane = threadIdx.x & 63;
    int n = blockIdx.x * 4 + wid;
    if (n >= N_NODES) return;
    int s = lane >> 3, q4 = (lane & 7) * 4;
    int4 po = *(const int4*)&poff4[n * 4];
    int4 rc = *(const int4*)&rcnt4[n * 4];
    int pc0 = (rc.x + 7) & ~7, pc1 = (rc.y + 7) & ~7;
    int pc2 = (rc.z + 7) & ~7, pc3 = (rc.w + 7) & ~7;
    int mx = max(max(pc0, pc1), max(pc2, pc3));
    if (lane < 8)
        *(float4*)&sxr[wid][lane * 4] = *(const float4*)&xp[n * F_IN + lane * 4];

    const int* e0p = elist + po.x + s;
    const int* e1p = elist + po.y + s;
    const int* e2p = elist + po.z + s;
    const int* e3p = elist + po.w + s;
    float4 a0 = {0, 0, 0, 0}, a1 = a0, a2 = a0, a3 = a0;
    for (int eb = 0; eb < mx; eb += 16) {
        int t0a = e0p[eb], t0b = e0p[eb + 8];
        int t1a = e1p[eb], t1b = e1p[eb + 8];
        int t2a = e2p[eb], t2b = e2p[eb + 8];
        int t3a = e3p[eb], t3b = e3p[eb + 8];
        int p0a = (eb < pc0) ? t0a : N_NODES;
        int p1a = (eb < pc1) ? t1a : N_NODES;
        int p2a = (eb < pc2) ? t2a : N_NODES;
        int p3a = (eb < pc3) ? t3a : N_NODES;
        int p0b = (eb + 8 < pc0) ? t0b : N_NODES;
        int p1b = (eb + 8 < pc1) ? t1b : N_NODES;
        int p2b = (eb + 8 < pc2) ? t2b : N_NODES;
        int p3b = (eb + 8 < pc3) ? t3b : N_NODES;
        float4 v0a = *(const float4*)&xp[p0a * F_IN + q4];
        float4 v1a = *(const float4*)&xp[p1a * F_IN + q4];
        float4 v2a = *(const float4*)&xp[p2a * F_IN + q4];
        float4 v3a = *(const float4*)&xp[p3a * F_IN + q4];
        float4 v0b = *(const float4*)&xp[p0b * F_IN + q4];
        float4 v1b = *(const float4*)&xp[p1b * F_IN + q4];
        float4 v2b = *(const float4*)&xp[p2b * F_IN + q4];
        float4 v3b = *(const float4*)&xp[p3b * F_IN + q4];
        acc4(a0, v0a); acc4(a0, v0b);
        acc4(a1, v1a); acc4(a1, v1b);
        acc4(a2, v2a); acc4(a2, v2b);
        acc4(a3, v3a); acc4(a3, v3b);
    }
    red4(a0); red4(a1); red4(a2); red4(a3);
    if (lane < 8) {
        float s0 = inv[0 * N_NODES + n], s1 = inv[1 * N_NODES + n];
        float s2 = inv[2 * N_NODES + n], s3 = inv[3 * N_NODES + n];
        a0.x *= s0; a0.y *= s0; a0.z *= s0; a0.w *= s0;
        a1.x *= s1; a1.y *= s1; a1.z *= s1; a1.w *= s1;
        a2.x *= s2; a2.y *= s2; a2.z *= s2; a2.w *= s2;
        a3.x *= s3; a3.y *= s3; a3.z *= s3; a3.w *= s3;
        *(float4*)&sagg[wid][0][lane * 4] = a0;
        *(float4*)&sagg[wid][1][lane * 4] = a1;
        *(float4*)&sagg[wid][2][lane * 4] = a2;
        *(float4*)&sagg[wid][3][lane * 4] = a3;
    }
    // split-K epilogue: half 0 sums i=0..15, half 1 sums i=16..31
    int col = lane & 31, half = lane >> 5, ib = half * 16;
    float o = (half == 0) ? bb[col] : 0.0f;
#pragma unroll
    for (int k = 0; k < 16; ++k)
        o = fmaf(sxr[wid][ib + k], W_root[(ib + k) * H1 + col], o);
#pragma unroll
    for (int r = 0; r < R_REL; ++r)
#pragma unroll
        for (int k = 0; k < 16; ++k)
            o = fmaf(sagg[wid][r][ib + k],
                     W_rel[r * F_IN * H1 + (ib + k) * H1 + col], o);
    o += __shfl_xor(o, 32);
    if (half == 0) h1[n * H1 + col] = fmaxf(o, 0.0f);
}

// ---------------- 7. layer 2: same gather, 64-col epilogue ----------------
__global__ __launch_bounds__(256, 4) void layer2_kernel(
    const float* __restrict__ h1, const int* __restrict__ poff4,
    const int* __restrict__ rcnt4, const int* __restrict__ elist,
    const float* __restrict__ inv, const float* __restrict__ W_rel,
    const float* __restrict__ W_root, const float* __restrict__ bb,
    float* __restrict__ out2) {
    __shared__ float sxr[4][H1];
    __shared__ float sagg[4][R_REL][H1];
    int wid = threadIdx.x >> 6, lane = threadIdx.x & 63;
    int n = blockIdx.x * 4 + wid;
    if (n >= N_NODES) return;
    int s = lane >> 3, q4 = (lane & 7) * 4;
    int4 po = *(const int4*)&poff4[n * 4];
    int4 rc = *(const int4*)&rcnt4[n * 4];
    int pc0 = (rc.x + 7) & ~7, pc1 = (rc.y + 7) & ~7;
    int pc2 = (rc.z + 7) & ~7, pc3 = (rc.w + 7) & ~7;
    int mx = max(max(pc0, pc1), max(pc2, pc3));
    if (lane < 8)
        *(float4*)&sxr[wid][lane * 4] = *(const float4*)&h1[n * H1 + lane * 4];

    const int* e0p = elist + po.x + s;
    const int* e1p = elist + po.y + s;
    const int* e2p = elist + po.z + s;
    const int* e3p = elist + po.w + s;
    float4 a0 = {0, 0, 0, 0}, a1 = a0, a2 = a0, a3 = a0;
    for (int eb = 0; eb < mx; eb += 16) {
        int t0a = e0p[eb], t0b = e0p[eb + 8];
        int t1a = e1p[eb], t1b = e1p[eb + 8];
        int t2a = e2p[eb], t2b = e2p[eb + 8];
        int t3a = e3p[eb], t3b = e3p[eb + 8];
        int p0a = (eb < pc0) ? t0a : N_NODES;
        int p1a = (eb < pc1) ? t1a : N_NODES;
        int p2a = (eb < pc2) ? t2a : N_NODES;
        int p3a = (eb < pc3) ? t3a : N_NODES;
        int p0b = (eb + 8 < pc0) ? t0b : N_NODES;
        int p1b = (eb + 8 < pc1) ? t1b : N_NODES;
        int p2b = (eb + 8 < pc2) ? t2b : N_NODES;
        int p3b = (eb + 8 < pc3) ? t3b : N_NODES;
        float4 v0a = *(const float4*)&h1[p0a * H1 + q4];
        float4 v1a = *(const float4*)&h1[p1a * H1 + q4];
        float4 v2a = *(const float4*)&h1[p2a * H1 + q4];
        float4 v3a = *(const float4*)&h1[p3a * H1 + q4];
        float4 v0b = *(const float4*)&h1[p0b * H1 + q4];
        float4 v1b = *(const float4*)&h1[p1b * H1 + q4];
        float4 v2b = *(const float4*)&h1[p2b * H1 + q4];
        float4 v3b = *(const float4*)&h1[p3b * H1 + q4];
        acc4(a0, v0a); acc4(a0, v0b);
        acc4(a1, v1a); acc4(a1, v1b);
        acc4(a2, v2a); acc4(a2, v2b);
        acc4(a3, v3a); acc4(a3, v3b);
    }
    red4(a0); red4(a1); red4(a2); red4(a3);
    if (lane < 8) {
        float s0 = inv[0 * N_NODES + n], s1 = inv[1 * N_NODES + n];
        float s2 = inv[2 * N_NODES + n], s3 = inv[3 * N_NODES + n];
        a0.x *= s0; a0.y *= s0; a0.z *= s0; a0.w *= s0;
        a1.x *= s1; a1.y *= s1; a1.z *= s1; a1.w *= s1;
        a2.x *= s2; a2.y *= s2; a2.z *= s2; a2.w *= s2;
        a3.x *= s3; a3.y *= s3; a3.z *= s3; a3.w *= s3;
        *(float4*)&sagg[wid][0][lane * 4] = a0;
        *(float4*)&sagg[wid][1][lane * 4] = a1;
        *(float4*)&sagg[wid][2][lane * 4] = a2;
        *(float4*)&sagg[wid][3][lane * 4] = a3;
    }
    float o = bb[lane];
#pragma unroll
    for (int i = 0; i < H1; ++i)
        o = fmaf(sxr[wid][i], W_root[i * H2 + lane], o);
#pragma unroll
    for (int r = 0; r < R_REL; ++r)
#pragma unroll
        for (int i = 0; i < H1; ++i)
            o = fmaf(sagg[wid][r][i], W_rel[r * H1 * H2 + i * H2 + lane], o);
    out2[n * H2 + lane] = o;
}

// ---------------- 8. pooling: relu + segment max ----------------
#define POOL_NODES 32
__global__ __launch_bounds__(64) void pool_kernel(
    const float* __restrict__ out2, const int* __restrict__ batch,
    unsigned int* __restrict__ g) {
    int col = threadIdx.x;
    int n0 = blockIdx.x * POOL_NODES;
    if (n0 >= N_NODES) return;
    int n1 = n0 + POOL_NODES;
    if (n1 > N_NODES) n1 = N_NODES;
    int cur = batch[n0];
    float m = 0.0f;
    for (int n = n0; n < n1; ++n) {
        int bnow = batch[n];
        if (bnow != cur) {
            atomicMax(&g[cur * H2 + col], __float_as_uint(m));
            cur = bnow;
            m = 0.0f;
        }
        m = fmaxf(m, out2[n * H2 + col]);
    }
    atomicMax(&g[cur * H2 + col], __float_as_uint(m));
}

// ---------------- 9. MLP head ----------------
__global__ __launch_bounds__(256) void mlp_kernel(
    const unsigned int* __restrict__ gbits, const float* __restrict__ lin1_w,
    const float* __restrict__ lin1_b, const float* __restrict__ lin2_w,
    const float* __restrict__ lin2_b, float* __restrict__ out) {
    __shared__ float sg[G_BATCH][H2];
    __shared__ float sh[G_BATCH][H1];
    __shared__ float sw1[H2 * H1];
    for (int i = threadIdx.x; i < G_BATCH * H2; i += 256)
        sg[i / H2][i % H2] = __uint_as_float(gbits[i]);
    for (int i = threadIdx.x; i < H2 * H1; i += 256) sw1[i] = lin1_w[i];
    __syncthreads();
    for (int i = threadIdx.x; i < G_BATCH * H1; i += 256) {
        int gi = i / H1, c = i % H1;
        float a = lin1_b[c];
#pragma unroll
        for (int k = 0; k < H2; ++k) a = fmaf(sg[gi][k], sw1[k * H1 + c], a);
        sh[gi][c] = fmaxf(a, 0.0f);
    }
    __syncthreads();
    for (int i = threadIdx.x; i < G_BATCH * NC; i += 256) {
        int gi = i / NC, c = i % NC;
        float a = lin2_b[c];
#pragma unroll
        for (int k = 0; k < H1; ++k) a = fmaf(sh[gi][k], lin2_w[k * NC + c], a);
        out[gi * NC + c] = a;
    }
}

// ---------------- launch ----------------
extern "C" void kernel_launch(void* const* d_in, const int* in_sizes, int n_in,
                              void* d_out, int out_size, void* d_ws, size_t ws_size,
                              hipStream_t stream) {
    const float* x       = (const float*)d_in[0];
    const int*   eidx    = (const int*)d_in[1];
    const int*   etype   = (const int*)d_in[2];
    const int*   batch   = (const int*)d_in[3];
    const float* W1_rel  = (const float*)d_in[4];
    const float* W1_root = (const float*)d_in[5];
    const float* b1      = (const float*)d_in[6];
    const float* W2_rel  = (const float*)d_in[7];
    const float* W2_root = (const float*)d_in[8];
    const float* b2      = (const float*)d_in[9];
    const float* lin1_w  = (const float*)d_in[10];
    const float* lin1_b  = (const float*)d_in[11];
    const float* lin2_w  = (const float*)d_in[12];
    const float* lin2_b  = (const float*)d_in[13];
    const int* srcp = eidx;
    const int* dstp = eidx + N_EDGES;

    char* ws = (char*)d_ws;
    size_t o = 0;
    int*      bucketCursor = (int*)(ws + o);   o += (size_t)256 * 4;
    int*      partial      = (int*)(ws + o);   o += (size_t)256 * 4;
    float*    inv          = (float*)(ws + o); o += (size_t)R_REL * N_NODES * 4;
    int*      rcnt4        = (int*)(ws + o);   o += (size_t)R_REL * N_NODES * 4;
    int*      poff4        = (int*)(ws + o);   o += (size_t)R_REL * N_NODES * 4;
    int*      binned       = (int*)(ws + o);   o += (size_t)BKT * BCAP * 4;
    int*      elist        = (int*)(ws + o);   o += (size_t)(ELIST_CAP + 4096) * 4;
    unsigned* g            = (unsigned*)(ws + o); o += (size_t)G_BATCH * H2 * 4;
    float*    xp           = (float*)(ws + o); o += (size_t)(N_NODES + 1) * F_IN * 4;
    float*    h1           = (float*)(ws + o); o += (size_t)(N_NODES + 1) * H1 * 4;
    float*    out2         = (float*)(ws + o); o += (size_t)N_NODES * H2 * 4;
    // total ~49 MB

    hipMemsetAsync(g, 0, (size_t)G_BATCH * H2 * 4, stream);

    copyx_kernel<<<((N_NODES + 1) * F_IN + 255) / 256, 256, 0, stream>>>(
        x, xp, h1 + (size_t)N_NODES * H1, bucketCursor);
    bin_kernel<<<NBIN, 256, 0, stream>>>(srcp, dstp, etype, bucketCursor, binned);
    bcnt2_kernel<<<BKT, 256, 0, stream>>>(binned, bucketCursor, inv, rcnt4,
                                          partial);
    scanB_kernel<<<1, 256, 0, stream>>>(partial);
    scanC_kernel<<<BKT, 256, 0, stream>>>(rcnt4, partial, poff4);
    bscatter_kernel<<<BKT, 256, 0, stream>>>(binned, bucketCursor, poff4,
                                             rcnt4, elist);

    layer1_kernel<<<(N_NODES + 3) / 4, 256, 0, stream>>>(
        xp, poff4, rcnt4, elist, inv, W1_rel, W1_root, b1, h1);
    layer2_kernel<<<(N_NODES + 3) / 4, 256, 0, stream>>>(
        h1, poff4, rcnt4, elist, inv, W2_rel, W2_root, b2, out2);

    pool_kernel<<<(N_NODES + POOL_NODES - 1) / POOL_NODES, 64, 0, stream>>>(
        out2, batch, g);
    mlp_kernel<<<1, 256, 0, stream>>>(g, lin1_w, lin1_b, lin2_w, lin2_b,
                                      (float*)d_out);
}

// Round 14
// 311.159 us; speedup vs baseline: 1.0914x; 1.0914x over previous
//
#include <hip/hip_runtime.h>

#define N_NODES 50000
#define N_EDGES 1600000
#define R_REL 4
#define F_IN 32
#define H1 32
#define H2 64
#define NC 3
#define G_BATCH 64
#define BKT 196                        // buckets = ceil(N/256)
#define BCAP 8960                      // fixed slice capacity (mean 8192 + 8.5 sigma)
#define CHUNK 1600                     // edges per binning block
#define NBIN (N_EDGES / CHUNK)         // 1000 exactly
#define ELIST_CAP (N_EDGES + N_NODES * R_REL * 8)

// ---------------- 0. padded copy of x + zero rows + cursor init ----------------
__global__ __launch_bounds__(256) void copyx_kernel(const float* __restrict__ x,
                                                    float* __restrict__ xp,
                                                    float* __restrict__ h1zero,
                                                    int* __restrict__ bucketCursor) {
    int i = blockIdx.x * 256 + threadIdx.x;
    if (i < (N_NODES + 1) * F_IN)
        xp[i] = (i < N_NODES * F_IN) ? x[i] : 0.0f;
    if (i < H1) h1zero[i] = 0.0f;      // h1 row N (sentinel row for layer 2)
    if (i < BKT) bucketCursor[i] = i * BCAP;   // fixed-capacity slice bases
}

// ---------------- 1. bin edges into fixed-cap bucket slices (direct scatter) --
// record = src | type<<16 | dstLocal<<18
__global__ __launch_bounds__(256) void bin_kernel(const int* __restrict__ srcp,
                                                  const int* __restrict__ dstp,
                                                  const int* __restrict__ etype,
                                                  int* __restrict__ bucketCursor,
                                                  int* __restrict__ binned) {
    __shared__ int h[BKT];
    __shared__ int lc[BKT];
    for (int i = threadIdx.x; i < BKT; i += 256) { h[i] = 0; lc[i] = 0; }
    __syncthreads();
    int e0 = blockIdx.x * CHUNK;
    for (int e = e0 + threadIdx.x; e < e0 + CHUNK; e += 256)
        atomicAdd(&h[dstp[e] >> 8], 1);
    __syncthreads();
    for (int i = threadIdx.x; i < BKT; i += 256) {
        int c = h[i];
        h[i] = c ? atomicAdd(&bucketCursor[i], c) : 0;   // reserve slice
    }
    __syncthreads();
    for (int e = e0 + threadIdx.x; e < e0 + CHUNK; e += 256) {
        int d = dstp[e];
        int b = d >> 8;
        int rank = atomicAdd(&lc[b], 1);
        binned[h[b] + rank] = srcp[e] | (etype[e] << 16) | ((d & 0xFF) << 18);
    }
}

// ---------------- 2. per-(node,rel) counts + inv + padded-degree block sums ---
__global__ __launch_bounds__(256) void bcnt2_kernel(const int* __restrict__ binned,
                                                    const int* __restrict__ bucketCursor,
                                                    float* __restrict__ inv,
                                                    int* __restrict__ rcnt4,
                                                    int* __restrict__ partial) {
    __shared__ int cnt4[256 * R_REL];
    __shared__ int s[256];
    for (int i = threadIdx.x; i < 256 * R_REL; i += 256) cnt4[i] = 0;
    __syncthreads();
    int b = blockIdx.x;
    int i0 = b * BCAP, i1 = bucketCursor[b];
    for (int i = i0 + threadIdx.x; i < i1; i += 256) {
        int p = binned[i];
        atomicAdd(&cnt4[((p >> 18) & 0xFF) * R_REL + ((p >> 16) & 3)], 1);
    }
    __syncthreads();
    int n = b * 256 + threadIdx.x;
    int d = 0;
    if (n < N_NODES) {
        int4 w;
        int c0 = cnt4[threadIdx.x * 4 + 0];
        int c1 = cnt4[threadIdx.x * 4 + 1];
        int c2 = cnt4[threadIdx.x * 4 + 2];
        int c3 = cnt4[threadIdx.x * 4 + 3];
        inv[0 * N_NODES + n] = 1.0f / (float)(c0 > 1 ? c0 : 1);
        inv[1 * N_NODES + n] = 1.0f / (float)(c1 > 1 ? c1 : 1);
        inv[2 * N_NODES + n] = 1.0f / (float)(c2 > 1 ? c2 : 1);
        inv[3 * N_NODES + n] = 1.0f / (float)(c3 > 1 ? c3 : 1);
        w.x = c0; w.y = c1; w.z = c2; w.w = c3;
        *(int4*)&rcnt4[n * 4] = w;
        d = ((c0 + 7) & ~7) + ((c1 + 7) & ~7) + ((c2 + 7) & ~7) + ((c3 + 7) & ~7);
    }
    s[threadIdx.x] = d;
    __syncthreads();
    for (int w = 128; w > 0; w >>= 1) {
        if (threadIdx.x < w) s[threadIdx.x] += s[threadIdx.x + w];
        __syncthreads();
    }
    if (threadIdx.x == 0) partial[b] = s[0];   // raw block sum (scanC self-scans)
}

// ---------------- 3. per-(node,rel) padded sub-offsets (self-prefixed) -------
// Each block computes its own prefix of partial[] (<=196 ints) — scanB deleted.
__global__ __launch_bounds__(256) void scanC_kernel(const int* __restrict__ rcnt4,
                                                    const int* __restrict__ partial,
                                                    int* __restrict__ poff4) {
    __shared__ int s[256];
    __shared__ int pre;
    int t = threadIdx.x;
    int pv = (t < blockIdx.x) ? partial[t] : 0;   // BKT <= 256
    s[t] = pv;
    __syncthreads();
    for (int w = 128; w > 0; w >>= 1) {
        if (t < w) s[t] += s[t + w];
        __syncthreads();
    }
    if (t == 0) pre = s[0];
    __syncthreads();

    int n = blockIdx.x * 256 + t;
    int p0 = 0, p1 = 0, p2 = 0, p3 = 0, d = 0;
    if (n < N_NODES) {
        int4 rc = *(const int4*)&rcnt4[n * 4];
        p0 = (rc.x + 7) & ~7;
        p1 = (rc.y + 7) & ~7;
        p2 = (rc.z + 7) & ~7;
        p3 = (rc.w + 7) & ~7;
        d = p0 + p1 + p2 + p3;
    }
    s[t] = d;
    __syncthreads();
    for (int w = 1; w < 256; w <<= 1) {
        int tv = (t >= w) ? s[t - w] : 0;
        __syncthreads();
        s[t] += tv;
        __syncthreads();
    }
    if (n < N_NODES) {
        int base = pre + s[t] - d;
        int4 w;
        w.x = base;
        w.y = base + p0;
        w.z = base + p0 + p1;
        w.w = base + p0 + p1 + p2;
        *(int4*)&poff4[n * 4] = w;
    }
}

// ---------------- 4. final CSR scatter, rel-sorted + sentinel padding --------
__global__ __launch_bounds__(256) void bscatter_kernel(const int* __restrict__ binned,
                                                       const int* __restrict__ bucketCursor,
                                                       const int* __restrict__ poff4,
                                                       const int* __restrict__ rcnt4,
                                                       int* __restrict__ elist) {
    __shared__ int cur[256 * 4];
    int b = blockIdx.x, t = threadIdx.x;
    int n = b * 256 + t;
    int4 po = make_int4(0, 0, 0, 0);
    if (n < N_NODES) po = *(const int4*)&poff4[n * 4];
    cur[t * 4 + 0] = po.x;
    cur[t * 4 + 1] = po.y;
    cur[t * 4 + 2] = po.z;
    cur[t * 4 + 3] = po.w;
    __syncthreads();
    int i0 = b * BCAP, i1 = bucketCursor[b];
    for (int i = i0 + t; i < i1; i += 256) {
        int p = binned[i];
        int pos = atomicAdd(&cur[((p >> 18) & 0xFF) * 4 + ((p >> 16) & 3)], 1);
        elist[pos] = p & 0xFFFF;       // src only (rel implied by segment)
    }
    __syncthreads();
    if (n < N_NODES) {
        int4 rc = *(const int4*)&rcnt4[n * 4];
        int rcv[4] = {rc.x, rc.y, rc.z, rc.w};
        int pov[4] = {po.x, po.y, po.z, po.w};
#pragma unroll
        for (int r = 0; r < R_REL; ++r) {
            int e = cur[t * 4 + r];
            int pe = pov[r] + ((rcv[r] + 7) & ~7);
            for (; e < pe; ++e) elist[e] = N_NODES;   // zero-row sentinel
        }
    }
}

// ---------------- 5. layer 1: 8 nodes/block, 32 lanes/node, shfl gather ------
// R6-MEASURED form (layer2=86.7us): one coalesced 128B row read per edge,
// 8-deep gather batches via shfl(.,j,8) broadcast. (256,8): VGPR 32, no spill.
__global__ __launch_bounds__(256, 8) void layer1_kernel(
    const float* __restrict__ xp, const int* __restrict__ poff4,
    const int* __restrict__ rcnt4, const int* __restrict__ elist,
    const float* __restrict__ inv, const float* __restrict__ W_rel,
    const float* __restrict__ W_root, const float* __restrict__ bb,
    float* __restrict__ h1) {
    __shared__ float sxr[8][F_IN];
    __shared__ float sagg[8][R_REL][F_IN];

    int ln = threadIdx.x >> 5, c = threadIdx.x & 31;
    int n = blockIdx.x * 8 + ln;
    if (n >= N_NODES) return;

    sxr[ln][c] = xp[n * F_IN + c];
    int4 po = *(const int4*)&poff4[n * 4];
    int4 rc = *(const int4*)&rcnt4[n * 4];
    int pov[4] = {po.x, po.y, po.z, po.w};
    int rcv[4] = {rc.x, rc.y, rc.z, rc.w};
    int c7 = c & 7;
#pragma unroll
    for (int r = 0; r < R_REL; ++r) {
        int sb = pov[r];
        int pc = (rcv[r] + 7) & ~7;
        float a = 0.0f;
        for (int eb = 0; eb < pc; eb += 8) {
            int pv = elist[sb + eb + c7];
            float v[8];
#pragma unroll
            for (int j = 0; j < 8; ++j) {
                int p = __shfl(pv, j, 8);
                v[j] = xp[p * F_IN + c];
            }
#pragma unroll
            for (int j = 0; j < 8; ++j) a += v[j];
        }
        sagg[ln][r][c] = a * inv[r * N_NODES + n];
    }

    float o = bb[c];
#pragma unroll
    for (int i = 0; i < F_IN; ++i)
        o = fmaf(sxr[ln][i], W_root[i * H1 + c], o);
#pragma unroll
    for (int r = 0; r < R_REL; ++r)
#pragma unroll
        for (int i = 0; i < F_IN; ++i)
            o = fmaf(sagg[ln][r][i], W_rel[r * F_IN * H1 + i * H1 + c], o);
    h1[n * H1 + c] = fmaxf(o, 0.0f);
}

// ---------------- 6. layer 2: same, each lane does 2 of 64 out cols ----------
__global__ __launch_bounds__(256, 8) void layer2_kernel(
    const float* __restrict__ h1, const int* __restrict__ poff4,
    const int* __restrict__ rcnt4, const int* __restrict__ elist,
    const float* __restrict__ inv, const float* __restrict__ W_rel,
    const float* __restrict__ W_root, const float* __restrict__ bb,
    float* __restrict__ out2) {
    __shared__ float sxr[8][H1];
    __shared__ float sagg[8][R_REL][H1];

    int ln = threadIdx.x >> 5, c = threadIdx.x & 31;
    int n = blockIdx.x * 8 + ln;
    if (n >= N_NODES) return;

    sxr[ln][c] = h1[n * H1 + c];
    int4 po = *(const int4*)&poff4[n * 4];
    int4 rc = *(const int4*)&rcnt4[n * 4];
    int pov[4] = {po.x, po.y, po.z, po.w};
    int rcv[4] = {rc.x, rc.y, rc.z, rc.w};
    int c7 = c & 7;
#pragma unroll
    for (int r = 0; r < R_REL; ++r) {
        int sb = pov[r];
        int pc = (rcv[r] + 7) & ~7;
        float a = 0.0f;
        for (int eb = 0; eb < pc; eb += 8) {
            int pv = elist[sb + eb + c7];
            float v[8];
#pragma unroll
            for (int j = 0; j < 8; ++j) {
                int p = __shfl(pv, j, 8);
                v[j] = h1[p * H1 + c];
            }
#pragma unroll
            for (int j = 0; j < 8; ++j) a += v[j];
        }
        sagg[ln][r][c] = a * inv[r * N_NODES + n];
    }

    float o0 = bb[c], o1 = bb[c + 32];
#pragma unroll
    for (int i = 0; i < H1; ++i) {
        float xv = sxr[ln][i];
        o0 = fmaf(xv, W_root[i * H2 + c], o0);
        o1 = fmaf(xv, W_root[i * H2 + c + 32], o1);
    }
#pragma unroll
    for (int r = 0; r < R_REL; ++r)
#pragma unroll
        for (int i = 0; i < H1; ++i) {
            float av = sagg[ln][r][i];
            o0 = fmaf(av, W_rel[r * H1 * H2 + i * H2 + c], o0);
            o1 = fmaf(av, W_rel[r * H1 * H2 + i * H2 + c + 32], o1);
        }
    out2[n * H2 + c] = o0;
    out2[n * H2 + c + 32] = o1;
}

// ---------------- 7. pooling: relu + segment max ----------------
#define POOL_NODES 32
__global__ __launch_bounds__(64) void pool_kernel(
    const float* __restrict__ out2, const int* __restrict__ batch,
    unsigned int* __restrict__ g) {
    int col = threadIdx.x;
    int n0 = blockIdx.x * POOL_NODES;
    if (n0 >= N_NODES) return;
    int n1 = n0 + POOL_NODES;
    if (n1 > N_NODES) n1 = N_NODES;
    int cur = batch[n0];
    float m = 0.0f;
    for (int n = n0; n < n1; ++n) {
        int bnow = batch[n];
        if (bnow != cur) {
            atomicMax(&g[cur * H2 + col], __float_as_uint(m));
            cur = bnow;
            m = 0.0f;
        }
        m = fmaxf(m, out2[n * H2 + col]);
    }
    atomicMax(&g[cur * H2 + col], __float_as_uint(m));
}

// ---------------- 8. MLP head ----------------
__global__ __launch_bounds__(256) void mlp_kernel(
    const unsigned int* __restrict__ gbits, const float* __restrict__ lin1_w,
    const float* __restrict__ lin1_b, const float* __restrict__ lin2_w,
    const float* __restrict__ lin2_b, float* __restrict__ out) {
    __shared__ float sg[G_BATCH][H2];
    __shared__ float sh[G_BATCH][H1];
    __shared__ float sw1[H2 * H1];
    for (int i = threadIdx.x; i < G_BATCH * H2; i += 256)
        sg[i / H2][i % H2] = __uint_as_float(gbits[i]);
    for (int i = threadIdx.x; i < H2 * H1; i += 256) sw1[i] = lin1_w[i];
    __syncthreads();
    for (int i = threadIdx.x; i < G_BATCH * H1; i += 256) {
        int gi = i / H1, c = i % H1;
        float a = lin1_b[c];
#pragma unroll
        for (int k = 0; k < H2; ++k) a = fmaf(sg[gi][k], sw1[k * H1 + c], a);
        sh[gi][c] = fmaxf(a, 0.0f);
    }
    __syncthreads();
    for (int i = threadIdx.x; i < G_BATCH * NC; i += 256) {
        int gi = i / NC, c = i % NC;
        float a = lin2_b[c];
#pragma unroll
        for (int k = 0; k < H1; ++k) a = fmaf(sh[gi][k], lin2_w[k * NC + c], a);
        out[gi * NC + c] = a;
    }
}

// ---------------- launch ----------------
extern "C" void kernel_launch(void* const* d_in, const int* in_sizes, int n_in,
                              void* d_out, int out_size, void* d_ws, size_t ws_size,
                              hipStream_t stream) {
    const float* x       = (const float*)d_in[0];
    const int*   eidx    = (const int*)d_in[1];
    const int*   etype   = (const int*)d_in[2];
    const int*   batch   = (const int*)d_in[3];
    const float* W1_rel  = (const float*)d_in[4];
    const float* W1_root = (const float*)d_in[5];
    const float* b1      = (const float*)d_in[6];
    const float* W2_rel  = (const float*)d_in[7];
    const float* W2_root = (const float*)d_in[8];
    const float* b2      = (const float*)d_in[9];
    const float* lin1_w  = (const float*)d_in[10];
    const float* lin1_b  = (const float*)d_in[11];
    const float* lin2_w  = (const float*)d_in[12];
    const float* lin2_b  = (const float*)d_in[13];
    const int* srcp = eidx;
    const int* dstp = eidx + N_EDGES;

    char* ws = (char*)d_ws;
    size_t o = 0;
    int*      bucketCursor = (int*)(ws + o);   o += (size_t)256 * 4;
    int*      partial      = (int*)(ws + o);   o += (size_t)256 * 4;
    float*    inv          = (float*)(ws + o); o += (size_t)R_REL * N_NODES * 4;
    int*      rcnt4        = (int*)(ws + o);   o += (size_t)R_REL * N_NODES * 4;
    int*      poff4        = (int*)(ws + o);   o += (size_t)R_REL * N_NODES * 4;
    int*      binned       = (int*)(ws + o);   o += (size_t)BKT * BCAP * 4;
    int*      elist        = (int*)(ws + o);   o += (size_t)(ELIST_CAP + 4096) * 4;
    unsigned* g            = (unsigned*)(ws + o); o += (size_t)G_BATCH * H2 * 4;
    float*    xp           = (float*)(ws + o); o += (size_t)(N_NODES + 1) * F_IN * 4;
    float*    h1           = (float*)(ws + o); o += (size_t)(N_NODES + 1) * H1 * 4;
    float*    out2         = (float*)(ws + o); o += (size_t)N_NODES * H2 * 4;
    // total ~49 MB

    hipMemsetAsync(g, 0, (size_t)G_BATCH * H2 * 4, stream);

    copyx_kernel<<<((N_NODES + 1) * F_IN + 255) / 256, 256, 0, stream>>>(
        x, xp, h1 + (size_t)N_NODES * H1, bucketCursor);
    bin_kernel<<<NBIN, 256, 0, stream>>>(srcp, dstp, etype, bucketCursor, binned);
    bcnt2_kernel<<<BKT, 256, 0, stream>>>(binned, bucketCursor, inv, rcnt4,
                                          partial);
    scanC_kernel<<<BKT, 256, 0, stream>>>(rcnt4, partial, poff4);
    bscatter_kernel<<<BKT, 256, 0, stream>>>(binned, bucketCursor, poff4,
                                             rcnt4, elist);

    layer1_kernel<<<(N_NODES + 7) / 8, 256, 0, stream>>>(
        xp, poff4, rcnt4, elist, inv, W1_rel, W1_root, b1, h1);
    layer2_kernel<<<(N_NODES + 7) / 8, 256, 0, stream>>>(
        h1, poff4, rcnt4, elist, inv, W2_rel, W2_root, b2, out2);

    pool_kernel<<<(N_NODES + POOL_NODES - 1) / POOL_NODES, 64, 0, stream>>>(
        out2, batch, g);
    mlp_kernel<<<1, 256, 0, stream>>>(g, lin1_w, lin1_b, lin2_w, lin2_b,
                                      (float*)d_out);
}